// Round 7
// baseline (888.569 us; speedup 1.0000x reference)
//
#include <hip/hip_runtime.h>

#define N_NODES 100000
#define N_EDGES 1000000
#define D_FEAT  6
#define HIDDEN  300
#define HID_P   320          // padded hidden (multiple of 32)
#define MSG     100
#define OUTC    200          // 2*MSG
#define MT      64           // edges per block
#define NT_H    (HID_P/16)   // 20 feature tiles for hidden layers
#define NT_M    13           // 13 feature tiles for messages (208 padded)
#define KS_H    (HID_P/32)   // 10 k-steps of 32

typedef __bf16 bf16_t;
typedef __bf16 bf16x8 __attribute__((ext_vector_type(8)));
typedef __bf16 bf16x4 __attribute__((ext_vector_type(4)));
typedef float  floatx4 __attribute__((ext_vector_type(4)));

// ---------------- prep (weight pack) + base MAE loss, merged --------------------
// Frag-order pack: chunk of 512 el = one (ft,ks) fragment: el = ((ft*KS+ks)*64+lane)*8+j,
// element = W[k][n], n = ft*16+(lane&15), k = ks*32+(lane>>4)*8+j, zero-padded.
#define PREP_BLOCKS 700
#define LOSS_BLOCKS 200
__global__ void prep_kernel(const float* __restrict__ W1, const float* __restrict__ W2,
                            const float* __restrict__ W3, bf16_t* __restrict__ W1P,
                            bf16_t* __restrict__ W2P, bf16_t* __restrict__ W3P,
                            const float* __restrict__ y, const float* __restrict__ t,
                            float* __restrict__ out) {
    if (blockIdx.x >= PREP_BLOCKS) {
        float s = 0.f;
        for (int i = (blockIdx.x - PREP_BLOCKS) * blockDim.x + threadIdx.x;
             i < N_NODES * 2; i += LOSS_BLOCKS * blockDim.x)
            s += fabsf(y[i] - t[i]);
        #pragma unroll
        for (int off = 32; off; off >>= 1) s += __shfl_down(s, off);
        __shared__ float red[4];
        if ((threadIdx.x & 63) == 0) red[threadIdx.x >> 6] = s;
        __syncthreads();
        if (threadIdx.x == 0)
            atomicAdd(out, (red[0] + red[1] + red[2] + red[3]) * (1.0f / N_NODES));
        return;
    }
    const int n1 = NT_H * 512;
    const int n2 = NT_H * KS_H * 512;
    const int n3 = NT_M * KS_H * 512;
    const int total = n1 + n2 + n3;
    for (int id = blockIdx.x * blockDim.x + threadIdx.x; id < total;
         id += PREP_BLOCKS * blockDim.x) {
        if (id < n1) {
            int nt = id >> 9, rem = id & 511, lane = rem >> 3, j = rem & 7;
            int n = nt * 16 + (lane & 15), k = (lane >> 4) * 8 + j;
            float v = (n < HIDDEN && k < 2 * D_FEAT) ? W1[k * HIDDEN + n] : 0.f;
            W1P[id] = (bf16_t)v;
        } else if (id < n1 + n2) {
            int r = id - n1;
            int chunk = r >> 9, rem = r & 511, lane = rem >> 3, j = rem & 7;
            int ks = chunk % KS_H, nt = chunk / KS_H;
            int n = nt * 16 + (lane & 15), k = ks * 32 + (lane >> 4) * 8 + j;
            float v = (n < HIDDEN && k < HIDDEN) ? W2[k * HIDDEN + n] : 0.f;
            W2P[r] = (bf16_t)v;
        } else {
            int r = id - n1 - n2;
            int chunk = r >> 9, rem = r & 511, lane = rem >> 3, j = rem & 7;
            int ks = chunk % KS_H, nt = chunk / KS_H;
            int n = nt * 16 + (lane & 15), k = ks * 32 + (lane >> 4) * 8 + j;
            float v = (n < OUTC && k < HIDDEN) ? W3[k * OUTC + n] : 0.f;
            W3P[r] = (bf16_t)v;
        }
    }
}

// ---------------- fused edge MLP + KL ------------------------------------------
// 256 threads = 4 waves, MT=64 (4 edge-tiles). Wave w owns 5 feature-tiles
// f = w+4t for GEMM1/2 (20/4), and f = w+4t (f<13) for GEMM3. Halves per-edge
// H-operand LDS traffic vs 8-wave R4 (4 waves read hb instead of 8).
// LDS = Hf only, 40960 B exactly -> 4 blocks/CU (160 KB), 16 waves/CU,
// 4 waves/SIMD -> 128-reg budget; peak ~115 (80 acc AGPR + 16 hb + misc).
// A1f (GEMM1 input frags, 4 KB) ALIASES Hf[0..2047]: barrier after all waves
// load their GEMM1 fragments, before the epilogue overwrites. Block reduction
// also aliases Hf (after GEMM3 reads complete).
// Layouts (verified R1-R4, absmax 0): operand-swapped D = mfma(A=W, B=H):
// A: m=lane&15, k=(lane>>4)*8+j; B: n=lane&15(edge), k=(lane>>4)*8+j;
// C/D: n(edge)=lane&15, m(feature)=(lane>>4)*4+reg.
__global__ __launch_bounds__(256, 4) void mlp_kernel(
    const float* __restrict__ x, const int* __restrict__ ei,
    const bf16_t* __restrict__ W1P, const bf16_t* __restrict__ W2P,
    const bf16_t* __restrict__ W3P,
    const float* __restrict__ b1, const float* __restrict__ b2,
    const float* __restrict__ b3, float* __restrict__ out) {
    __shared__ __align__(16) bf16_t Hf[4 * KS_H * 64 * 8];    // 40 KB exactly
    bf16_t* A1f = Hf;                                          // aliased 4 KB

    const int tid  = threadIdx.x;
    const int w    = tid >> 6, lane = tid & 63;
    const int q    = lane >> 4, l16 = lane & 15;
    const long e0 = (long)blockIdx.x * MT;

    // zero A1f region (k >= 12 must be 0 for GEMM1's padded K=32): 256x16B = 4KB
    ((uint4*)A1f)[tid] = (uint4){0u, 0u, 0u, 0u};
    __syncthreads();
    // gather: edge features -> A1f fragment order: feat k of edge (et*16+ml)
    // at lane' = ml + 16*(k>>3), slot j = k&7
    if (tid < 2 * MT) {
        int m = tid >> 1, side = tid & 1;
        int node = ei[(long)side * N_EDGES + e0 + m];
        const float* xr = x + (long)node * D_FEAT;
        int et = m >> 4, ml = m & 15;
        #pragma unroll
        for (int c = 0; c < D_FEAT; c++) {
            int k = side * D_FEAT + c;
            int lp = ml + 16 * (k >> 3);
            A1f[(et * 64 + lp) * 8 + (k & 7)] = (bf16_t)xr[c];
        }
    }
    __syncthreads();

    // ---- GEMM1: h1 = relu(e @ W1 + b1), K=32 (one step), 5 tiles/wave ----
    floatx4 acc1[5][4];
    {
        bf16x8 hb[4];
        #pragma unroll
        for (int e = 0; e < 4; e++)
            hb[e] = *(const bf16x8*)&A1f[(e * 64 + lane) * 8];
        #pragma unroll
        for (int t = 0; t < 5; t++) {
            bf16x8 wf = *(const bf16x8*)&W1P[((w + 4 * t) * 64 + lane) * 8];
            #pragma unroll
            for (int e = 0; e < 4; e++) {
                floatx4 z = {0.f, 0.f, 0.f, 0.f};
                acc1[t][e] = __builtin_amdgcn_mfma_f32_16x16x32_bf16(wf, hb[e], z, 0, 0, 0);
            }
        }
        __syncthreads();   // all A1f fragment loads done before Hf overwrites alias
    }
    #pragma unroll
    for (int t = 0; t < 5; t++) {
        int n0 = (w + 4 * t) * 16 + 4 * q;           // 4 consecutive features
        floatx4 bv = (n0 < HIDDEN) ? *(const floatx4*)&b1[n0]
                                   : (floatx4){0.f, 0.f, 0.f, 0.f};
        int ks = n0 >> 5, lp = l16 + 16 * ((n0 >> 3) & 3), j0 = n0 & 7;
        #pragma unroll
        for (int e = 0; e < 4; e++) {
            bf16x4 pk;
            #pragma unroll
            for (int r = 0; r < 4; r++)
                pk[r] = (bf16_t)fmaxf(acc1[t][e][r] + bv[r], 0.f);
            *(bf16x4*)&Hf[((e * KS_H + ks) * 64 + lp) * 8 + j0] = pk;
        }
    }
    __syncthreads();

    // ---- GEMM2: h2 = relu(h1 @ W2 + b2), K=320, 5 tiles/wave ----
    floatx4 acc2[5][4];
    #pragma unroll
    for (int t = 0; t < 5; t++)
        #pragma unroll
        for (int e = 0; e < 4; e++) acc2[t][e] = (floatx4){0.f, 0.f, 0.f, 0.f};
    for (int ks = 0; ks < KS_H; ks++) {
        bf16x8 hb[4];
        #pragma unroll
        for (int e = 0; e < 4; e++)
            hb[e] = *(const bf16x8*)&Hf[((e * KS_H + ks) * 64 + lane) * 8];
        #pragma unroll
        for (int t = 0; t < 5; t++) {
            bf16x8 wf = *(const bf16x8*)&W2P[(((w + 4 * t) * KS_H + ks) * 64 + lane) * 8];
            #pragma unroll
            for (int e = 0; e < 4; e++)
                acc2[t][e] = __builtin_amdgcn_mfma_f32_16x16x32_bf16(wf, hb[e], acc2[t][e], 0, 0, 0);
        }
    }
    __syncthreads();   // all Hf(h1) reads done before overwrite
    #pragma unroll
    for (int t = 0; t < 5; t++) {
        int n0 = (w + 4 * t) * 16 + 4 * q;
        floatx4 bv = (n0 < HIDDEN) ? *(const floatx4*)&b2[n0]
                                   : (floatx4){0.f, 0.f, 0.f, 0.f};
        int ks = n0 >> 5, lp = l16 + 16 * ((n0 >> 3) & 3), j0 = n0 & 7;
        #pragma unroll
        for (int e = 0; e < 4; e++) {
            bf16x4 pk;
            #pragma unroll
            for (int r = 0; r < 4; r++)
                pk[r] = (bf16_t)fmaxf(acc2[t][e][r] + bv[r], 0.f);
            *(bf16x4*)&Hf[((e * KS_H + ks) * 64 + lp) * 8 + j0] = pk;
        }
    }
    __syncthreads();

    // ---- GEMM3: messages = h2 @ W3 + b3, KL in-register; tiles f=w+4t<13 ----
    floatx4 acc3[4][4];
    #pragma unroll
    for (int t = 0; t < 4; t++)
        #pragma unroll
        for (int e = 0; e < 4; e++) acc3[t][e] = (floatx4){0.f, 0.f, 0.f, 0.f};
    for (int ks = 0; ks < KS_H; ks++) {
        bf16x8 hb[4];
        #pragma unroll
        for (int e = 0; e < 4; e++)
            hb[e] = *(const bf16x8*)&Hf[((e * KS_H + ks) * 64 + lane) * 8];
        #pragma unroll
        for (int t = 0; t < 4; t++) {
            if (w + 4 * t < NT_M) {
                bf16x8 wf = *(const bf16x8*)&W3P[(((w + 4 * t) * KS_H + ks) * 64 + lane) * 8];
                #pragma unroll
                for (int e = 0; e < 4; e++)
                    acc3[t][e] = __builtin_amdgcn_mfma_f32_16x16x32_bf16(wf, hb[e], acc3[t][e], 0, 0, 0);
            }
        }
    }
    float s = 0.f;
    #pragma unroll
    for (int t = 0; t < 4; t++) {
        if (w + 4 * t < NT_M) {
            int n0 = (w + 4 * t) * 16 + 4 * q;       // 4 consecutive features
            if (n0 < OUTC) {                          // 4-runs never straddle 100/200
                floatx4 bv = *(const floatx4*)&b3[n0];
                bool is_mu = (n0 < MSG);
                #pragma unroll
                for (int e = 0; e < 4; e++)
                    #pragma unroll
                    for (int r = 0; r < 4; r++) {
                        float v = acc3[t][e][r] + bv[r];
                        if (is_mu) s += 0.5f * v * v;
                        else       s += 0.5f * (__expf(v) - v - 1.f);
                    }
            }
        }
    }
    #pragma unroll
    for (int off = 32; off; off >>= 1) s += __shfl_down(s, off);
    __syncthreads();                 // Hf dead (all GEMM3 reads done) -> reuse for red
    float* red = (float*)Hf;
    if (lane == 0) red[w] = s;
    __syncthreads();
    if (tid == 0)
        atomicAdd(out, (red[0] + red[1] + red[2] + red[3]) * (1.0f / N_EDGES));
}

extern "C" void kernel_launch(void* const* d_in, const int* in_sizes, int n_in,
                              void* d_out, int out_size, void* d_ws, size_t ws_size,
                              hipStream_t stream) {
    const float* x      = (const float*)d_in[0];
    const int*   ei     = (const int*)d_in[1];
    const float* y      = (const float*)d_in[2];
    const float* target = (const float*)d_in[3];
    const float* W1     = (const float*)d_in[4];
    const float* b1     = (const float*)d_in[5];
    const float* W2     = (const float*)d_in[6];
    const float* b2     = (const float*)d_in[7];
    const float* W3     = (const float*)d_in[8];
    const float* b3     = (const float*)d_in[9];
    float* out = (float*)d_out;

    bf16_t* W1P = (bf16_t*)d_ws;
    bf16_t* W2P = W1P + NT_H * 512;
    bf16_t* W3P = W2P + NT_H * KS_H * 512;

    hipMemsetAsync(d_out, 0, sizeof(float), stream);
    prep_kernel<<<PREP_BLOCKS + LOSS_BLOCKS, 256, 0, stream>>>(
        W1, W2, W3, W1P, W2P, W3P, y, target, out);
    mlp_kernel<<<N_EDGES / MT, 256, 0, stream>>>(x, ei, W1P, W2P, W3P, b1, b2, b3, out);
}

// Round 8
// 552.490 us; speedup vs baseline: 1.6083x; 1.6083x over previous
//
#include <hip/hip_runtime.h>

#define N_NODES 100000
#define N_EDGES 1000000
#define D_FEAT  6
#define HIDDEN  300
#define HID_P   320          // padded hidden (multiple of 32)
#define MSG     100
#define OUTC    200          // 2*MSG
#define MT      64           // edges per block
#define NT_H    (HID_P/16)   // 20 feature tiles for hidden layers
#define NT_M    13           // 13 feature tiles for messages (208 padded)
#define KS_H    (HID_P/32)   // 10 k-steps of 32

typedef __bf16 bf16_t;
typedef __bf16 bf16x8 __attribute__((ext_vector_type(8)));
typedef __bf16 bf16x4 __attribute__((ext_vector_type(4)));
typedef float  floatx4 __attribute__((ext_vector_type(4)));

// ---------------- prep (weight pack) + base MAE loss, merged --------------------
// Frag-order pack: chunk of 512 el = one (ft,ks) fragment: el = ((ft*KS+ks)*64+lane)*8+j,
// element = W[k][n], n = ft*16+(lane&15), k = ks*32+(lane>>4)*8+j, zero-padded.
#define PREP_BLOCKS 700
#define LOSS_BLOCKS 200
__global__ void prep_kernel(const float* __restrict__ W1, const float* __restrict__ W2,
                            const float* __restrict__ W3, bf16_t* __restrict__ W1P,
                            bf16_t* __restrict__ W2P, bf16_t* __restrict__ W3P,
                            const float* __restrict__ y, const float* __restrict__ t,
                            float* __restrict__ out) {
    if (blockIdx.x >= PREP_BLOCKS) {
        float s = 0.f;
        for (int i = (blockIdx.x - PREP_BLOCKS) * blockDim.x + threadIdx.x;
             i < N_NODES * 2; i += LOSS_BLOCKS * blockDim.x)
            s += fabsf(y[i] - t[i]);
        #pragma unroll
        for (int off = 32; off; off >>= 1) s += __shfl_down(s, off);
        __shared__ float red[4];
        if ((threadIdx.x & 63) == 0) red[threadIdx.x >> 6] = s;
        __syncthreads();
        if (threadIdx.x == 0)
            atomicAdd(out, (red[0] + red[1] + red[2] + red[3]) * (1.0f / N_NODES));
        return;
    }
    const int n1 = NT_H * 512;
    const int n2 = NT_H * KS_H * 512;
    const int n3 = NT_M * KS_H * 512;
    const int total = n1 + n2 + n3;
    for (int id = blockIdx.x * blockDim.x + threadIdx.x; id < total;
         id += PREP_BLOCKS * blockDim.x) {
        if (id < n1) {
            int nt = id >> 9, rem = id & 511, lane = rem >> 3, j = rem & 7;
            int n = nt * 16 + (lane & 15), k = (lane >> 4) * 8 + j;
            float v = (n < HIDDEN && k < 2 * D_FEAT) ? W1[k * HIDDEN + n] : 0.f;
            W1P[id] = (bf16_t)v;
        } else if (id < n1 + n2) {
            int r = id - n1;
            int chunk = r >> 9, rem = r & 511, lane = rem >> 3, j = rem & 7;
            int ks = chunk % KS_H, nt = chunk / KS_H;
            int n = nt * 16 + (lane & 15), k = ks * 32 + (lane >> 4) * 8 + j;
            float v = (n < HIDDEN && k < HIDDEN) ? W2[k * HIDDEN + n] : 0.f;
            W2P[r] = (bf16_t)v;
        } else {
            int r = id - n1 - n2;
            int chunk = r >> 9, rem = r & 511, lane = rem >> 3, j = rem & 7;
            int ks = chunk % KS_H, nt = chunk / KS_H;
            int n = nt * 16 + (lane & 15), k = ks * 32 + (lane >> 4) * 8 + j;
            float v = (n < OUTC && k < HIDDEN) ? W3[k * OUTC + n] : 0.f;
            W3P[r] = (bf16_t)v;
        }
    }
}

// ---------------- fused edge MLP + KL ------------------------------------------
// 256 threads = 4 waves, MT=64 (4 edge-tiles). Wave w owns 5 feature-tiles
// f = w+4t for GEMM1/2, f = w+4t (<13) for GEMM3. 4 waves = minimum per-edge
// LDS read traffic (∝ waves/16) that covers 20 nt with acc<=80.
// REGISTER MATH (R7 lesson): unified demand = 80 acc + 16 hb + 8 wf + ~30 misc
// ≈ 134 regs. launch_bounds(256,3) -> ~170-reg budget: fits, no spill.
// (256,4)'s 128 budget spilled ~70 dwords/thread -> 1.9 GB HBM scratch (R7).
// Occupancy: 3 blocks/CU (reg-limited), 12 waves/CU. LDS 40960 B/block.
// A1f aliases Hf[0..2047] (barrier after GEMM1 frag loads); reduction aliases
// Hf after GEMM3. Layouts (verified R1-R7, absmax 0), operand-swapped
// D = mfma(A=W, B=H): A: m=lane&15, k=(lane>>4)*8+j; B: n=lane&15(edge),
// k=(lane>>4)*8+j; C/D: n(edge)=lane&15, m(feature)=(lane>>4)*4+reg.
__global__ __launch_bounds__(256, 3) void mlp_kernel(
    const float* __restrict__ x, const int* __restrict__ ei,
    const bf16_t* __restrict__ W1P, const bf16_t* __restrict__ W2P,
    const bf16_t* __restrict__ W3P,
    const float* __restrict__ b1, const float* __restrict__ b2,
    const float* __restrict__ b3, float* __restrict__ out) {
    __shared__ __align__(16) bf16_t Hf[4 * KS_H * 64 * 8];    // 40 KB exactly
    bf16_t* A1f = Hf;                                          // aliased 4 KB

    const int tid  = threadIdx.x;
    const int w    = tid >> 6, lane = tid & 63;
    const int q    = lane >> 4, l16 = lane & 15;
    const long e0 = (long)blockIdx.x * MT;

    // zero A1f region (k >= 12 must be 0 for GEMM1's padded K=32): 256x16B = 4KB
    ((uint4*)A1f)[tid] = (uint4){0u, 0u, 0u, 0u};
    __syncthreads();
    // gather: edge features -> A1f fragment order: feat k of edge (et*16+ml)
    // at lane' = ml + 16*(k>>3), slot j = k&7
    if (tid < 2 * MT) {
        int m = tid >> 1, side = tid & 1;
        int node = ei[(long)side * N_EDGES + e0 + m];
        const float* xr = x + (long)node * D_FEAT;
        int et = m >> 4, ml = m & 15;
        #pragma unroll
        for (int c = 0; c < D_FEAT; c++) {
            int k = side * D_FEAT + c;
            int lp = ml + 16 * (k >> 3);
            A1f[(et * 64 + lp) * 8 + (k & 7)] = (bf16_t)xr[c];
        }
    }
    __syncthreads();

    // ---- GEMM1: h1 = relu(e @ W1 + b1), K=32 (one step), 5 tiles/wave ----
    floatx4 acc1[5][4];
    {
        bf16x8 hb[4];
        #pragma unroll
        for (int e = 0; e < 4; e++)
            hb[e] = *(const bf16x8*)&A1f[(e * 64 + lane) * 8];
        #pragma unroll
        for (int t = 0; t < 5; t++) {
            bf16x8 wf = *(const bf16x8*)&W1P[((w + 4 * t) * 64 + lane) * 8];
            #pragma unroll
            for (int e = 0; e < 4; e++) {
                floatx4 z = {0.f, 0.f, 0.f, 0.f};
                acc1[t][e] = __builtin_amdgcn_mfma_f32_16x16x32_bf16(wf, hb[e], z, 0, 0, 0);
            }
        }
        __syncthreads();   // all A1f fragment loads done before Hf overwrites alias
    }
    #pragma unroll
    for (int t = 0; t < 5; t++) {
        int n0 = (w + 4 * t) * 16 + 4 * q;           // 4 consecutive features
        floatx4 bv = (n0 < HIDDEN) ? *(const floatx4*)&b1[n0]
                                   : (floatx4){0.f, 0.f, 0.f, 0.f};
        int ks = n0 >> 5, lp = l16 + 16 * ((n0 >> 3) & 3), j0 = n0 & 7;
        #pragma unroll
        for (int e = 0; e < 4; e++) {
            bf16x4 pk;
            #pragma unroll
            for (int r = 0; r < 4; r++)
                pk[r] = (bf16_t)fmaxf(acc1[t][e][r] + bv[r], 0.f);
            *(bf16x4*)&Hf[((e * KS_H + ks) * 64 + lp) * 8 + j0] = pk;
        }
    }
    __syncthreads();

    // ---- GEMM2: h2 = relu(h1 @ W2 + b2), K=320, 5 tiles/wave ----
    floatx4 acc2[5][4];
    #pragma unroll
    for (int t = 0; t < 5; t++)
        #pragma unroll
        for (int e = 0; e < 4; e++) acc2[t][e] = (floatx4){0.f, 0.f, 0.f, 0.f};
    for (int ks = 0; ks < KS_H; ks++) {
        bf16x8 hb[4];
        #pragma unroll
        for (int e = 0; e < 4; e++)
            hb[e] = *(const bf16x8*)&Hf[((e * KS_H + ks) * 64 + lane) * 8];
        #pragma unroll
        for (int t = 0; t < 5; t++) {
            bf16x8 wf = *(const bf16x8*)&W2P[(((w + 4 * t) * KS_H + ks) * 64 + lane) * 8];
            #pragma unroll
            for (int e = 0; e < 4; e++)
                acc2[t][e] = __builtin_amdgcn_mfma_f32_16x16x32_bf16(wf, hb[e], acc2[t][e], 0, 0, 0);
        }
    }
    __syncthreads();   // all Hf(h1) reads done before overwrite
    #pragma unroll
    for (int t = 0; t < 5; t++) {
        int n0 = (w + 4 * t) * 16 + 4 * q;
        floatx4 bv = (n0 < HIDDEN) ? *(const floatx4*)&b2[n0]
                                   : (floatx4){0.f, 0.f, 0.f, 0.f};
        int ks = n0 >> 5, lp = l16 + 16 * ((n0 >> 3) & 3), j0 = n0 & 7;
        #pragma unroll
        for (int e = 0; e < 4; e++) {
            bf16x4 pk;
            #pragma unroll
            for (int r = 0; r < 4; r++)
                pk[r] = (bf16_t)fmaxf(acc2[t][e][r] + bv[r], 0.f);
            *(bf16x4*)&Hf[((e * KS_H + ks) * 64 + lp) * 8 + j0] = pk;
        }
    }
    __syncthreads();

    // ---- GEMM3: messages = h2 @ W3 + b3, KL in-register; tiles f=w+4t<13 ----
    floatx4 acc3[4][4];
    #pragma unroll
    for (int t = 0; t < 4; t++)
        #pragma unroll
        for (int e = 0; e < 4; e++) acc3[t][e] = (floatx4){0.f, 0.f, 0.f, 0.f};
    for (int ks = 0; ks < KS_H; ks++) {
        bf16x8 hb[4];
        #pragma unroll
        for (int e = 0; e < 4; e++)
            hb[e] = *(const bf16x8*)&Hf[((e * KS_H + ks) * 64 + lane) * 8];
        #pragma unroll
        for (int t = 0; t < 4; t++) {
            if (w + 4 * t < NT_M) {
                bf16x8 wf = *(const bf16x8*)&W3P[(((w + 4 * t) * KS_H + ks) * 64 + lane) * 8];
                #pragma unroll
                for (int e = 0; e < 4; e++)
                    acc3[t][e] = __builtin_amdgcn_mfma_f32_16x16x32_bf16(wf, hb[e], acc3[t][e], 0, 0, 0);
            }
        }
    }
    float s = 0.f;
    #pragma unroll
    for (int t = 0; t < 4; t++) {
        if (w + 4 * t < NT_M) {
            int n0 = (w + 4 * t) * 16 + 4 * q;       // 4 consecutive features
            if (n0 < OUTC) {                          // 4-runs never straddle 100/200
                floatx4 bv = *(const floatx4*)&b3[n0];
                bool is_mu = (n0 < MSG);
                #pragma unroll
                for (int e = 0; e < 4; e++)
                    #pragma unroll
                    for (int r = 0; r < 4; r++) {
                        float v = acc3[t][e][r] + bv[r];
                        if (is_mu) s += 0.5f * v * v;
                        else       s += 0.5f * (__expf(v) - v - 1.f);
                    }
            }
        }
    }
    #pragma unroll
    for (int off = 32; off; off >>= 1) s += __shfl_down(s, off);
    __syncthreads();                 // Hf dead (all GEMM3 reads done) -> reuse for red
    float* red = (float*)Hf;
    if (lane == 0) red[w] = s;
    __syncthreads();
    if (tid == 0)
        atomicAdd(out, (red[0] + red[1] + red[2] + red[3]) * (1.0f / N_EDGES));
}

extern "C" void kernel_launch(void* const* d_in, const int* in_sizes, int n_in,
                              void* d_out, int out_size, void* d_ws, size_t ws_size,
                              hipStream_t stream) {
    const float* x      = (const float*)d_in[0];
    const int*   ei     = (const int*)d_in[1];
    const float* y      = (const float*)d_in[2];
    const float* target = (const float*)d_in[3];
    const float* W1     = (const float*)d_in[4];
    const float* b1     = (const float*)d_in[5];
    const float* W2     = (const float*)d_in[6];
    const float* b2     = (const float*)d_in[7];
    const float* W3     = (const float*)d_in[8];
    const float* b3     = (const float*)d_in[9];
    float* out = (float*)d_out;

    bf16_t* W1P = (bf16_t*)d_ws;
    bf16_t* W2P = W1P + NT_H * 512;
    bf16_t* W3P = W2P + NT_H * KS_H * 512;

    hipMemsetAsync(d_out, 0, sizeof(float), stream);
    prep_kernel<<<PREP_BLOCKS + LOSS_BLOCKS, 256, 0, stream>>>(
        W1, W2, W3, W1P, W2P, W3P, y, target, out);
    mlp_kernel<<<N_EDGES / MT, 256, 0, stream>>>(x, ei, W1P, W2P, W3P, b1, b2, b3, out);
}

// Round 9
// 512.475 us; speedup vs baseline: 1.7339x; 1.0781x over previous
//
#include <hip/hip_runtime.h>

#define N_NODES 100000
#define N_EDGES 1000000
#define D_FEAT  6
#define HIDDEN  300
#define HID_P   320          // padded hidden (multiple of 32)
#define MSG     100
#define OUTC    200          // 2*MSG
#define MT      64           // edges per block
#define NT_H    (HID_P/16)   // 20 feature tiles for hidden layers
#define NT_M    13           // 13 feature tiles for messages (208 padded)
#define KS_H    (HID_P/32)   // 10 k-steps of 32

typedef __bf16 bf16_t;
typedef __bf16 bf16x8 __attribute__((ext_vector_type(8)));
typedef __bf16 bf16x4 __attribute__((ext_vector_type(4)));
typedef float  floatx4 __attribute__((ext_vector_type(4)));

// ---------------- prep (weight pack) + base MAE loss, merged --------------------
// Frag-order pack: chunk of 512 el = one (ft,ks) fragment: el = ((ft*KS+ks)*64+lane)*8+j,
// element = W[k][n], n = ft*16+(lane&15), k = ks*32+(lane>>4)*8+j, zero-padded.
#define PREP_BLOCKS 700
#define LOSS_BLOCKS 200
__global__ void prep_kernel(const float* __restrict__ W1, const float* __restrict__ W2,
                            const float* __restrict__ W3, bf16_t* __restrict__ W1P,
                            bf16_t* __restrict__ W2P, bf16_t* __restrict__ W3P,
                            const float* __restrict__ y, const float* __restrict__ t,
                            float* __restrict__ out) {
    if (blockIdx.x >= PREP_BLOCKS) {
        float s = 0.f;
        for (int i = (blockIdx.x - PREP_BLOCKS) * blockDim.x + threadIdx.x;
             i < N_NODES * 2; i += LOSS_BLOCKS * blockDim.x)
            s += fabsf(y[i] - t[i]);
        #pragma unroll
        for (int off = 32; off; off >>= 1) s += __shfl_down(s, off);
        __shared__ float red[4];
        if ((threadIdx.x & 63) == 0) red[threadIdx.x >> 6] = s;
        __syncthreads();
        if (threadIdx.x == 0)
            atomicAdd(out, (red[0] + red[1] + red[2] + red[3]) * (1.0f / N_NODES));
        return;
    }
    const int n1 = NT_H * 512;
    const int n2 = NT_H * KS_H * 512;
    const int n3 = NT_M * KS_H * 512;
    const int total = n1 + n2 + n3;
    for (int id = blockIdx.x * blockDim.x + threadIdx.x; id < total;
         id += PREP_BLOCKS * blockDim.x) {
        if (id < n1) {
            int nt = id >> 9, rem = id & 511, lane = rem >> 3, j = rem & 7;
            int n = nt * 16 + (lane & 15), k = (lane >> 4) * 8 + j;
            float v = (n < HIDDEN && k < 2 * D_FEAT) ? W1[k * HIDDEN + n] : 0.f;
            W1P[id] = (bf16_t)v;
        } else if (id < n1 + n2) {
            int r = id - n1;
            int chunk = r >> 9, rem = r & 511, lane = rem >> 3, j = rem & 7;
            int ks = chunk % KS_H, nt = chunk / KS_H;
            int n = nt * 16 + (lane & 15), k = ks * 32 + (lane >> 4) * 8 + j;
            float v = (n < HIDDEN && k < HIDDEN) ? W2[k * HIDDEN + n] : 0.f;
            W2P[r] = (bf16_t)v;
        } else {
            int r = id - n1 - n2;
            int chunk = r >> 9, rem = r & 511, lane = rem >> 3, j = rem & 7;
            int ks = chunk % KS_H, nt = chunk / KS_H;
            int n = nt * 16 + (lane & 15), k = ks * 32 + (lane >> 4) * 8 + j;
            float v = (n < OUTC && k < HIDDEN) ? W3[k * OUTC + n] : 0.f;
            W3P[r] = (bf16_t)v;
        }
    }
}

// ---------------- fused edge MLP + KL ------------------------------------------
// 512 threads = 8 waves in a 2(M)x4(N) grid: wm = wave>>2 owns edge-tiles
// {2wm, 2wm+1}; wn = wave&3 owns feature-tiles f = wn+4t (t<5 for GEMM1/2;
// GEMM3: t < (wn==0 ? 4 : 3), f<13).
// WHY 2x4 (R1-R8 evidence): waves/SIMD dominates (latency-bound kernel):
// 6/SIMD->420-433, 3/SIMD->538. acc/wave = 320/waves; 2x4 gives acc 40 ->
// spill-free at the (512,6) 85-reg budget (R2: VGPR 40, WRITE 488 KB),
// while 1x8's acc 48 spills (R4: 168 MB) and 4-wave's acc 80 spills hard
// (R7/R8). 2x4 also halves LDS reads vs 1x8: each edge-frag read by 4
// waves, 160 ds_read_b128/block. Cost: W-L2 traffic 2x (570 KB/block,
// ~23 TB/s < 34.5 ceiling — bounded at ~60 us by R2->R3 delta).
// LDS = Hf 40960 B only; A1f (4 KB) and reduction buffer alias it.
// Layouts (verified R1-R8, absmax 0), operand-swapped D = mfma(A=W, B=H):
// A: m=lane&15, k=(lane>>4)*8+j; B: n=lane&15(edge), k=(lane>>4)*8+j;
// C/D: n(edge)=lane&15, m(feature)=(lane>>4)*4+reg.
__global__ __launch_bounds__(512, 6) void mlp_kernel(
    const float* __restrict__ x, const int* __restrict__ ei,
    const bf16_t* __restrict__ W1P, const bf16_t* __restrict__ W2P,
    const bf16_t* __restrict__ W3P,
    const float* __restrict__ b1, const float* __restrict__ b2,
    const float* __restrict__ b3, float* __restrict__ out) {
    __shared__ __align__(16) bf16_t Hf[4 * KS_H * 64 * 8];    // 40 KB exactly
    bf16_t* A1f = Hf;                                          // aliased 4 KB

    const int tid  = threadIdx.x;
    const int wave = tid >> 6, lane = tid & 63;
    const int q    = lane >> 4, l16 = lane & 15;
    const int wm = wave >> 2, wn = wave & 3;
    const int eb = 2 * wm;                 // this wave's first edge-tile
    const int cnt3 = (wn == 0) ? 4 : 3;    // GEMM3 tiles: f = wn+4t < 13
    const long e0 = (long)blockIdx.x * MT;

    // zero A1f region (k >= 12 must be 0 for GEMM1's padded K=32): 512x8B = 4KB
    *(ulong*)&A1f[tid * 4] = 0ul;
    __syncthreads();
    // gather: edge features -> A1f fragment order: feat k of edge (et*16+ml)
    // at lane' = ml + 16*(k>>3), slot j = k&7
    if (tid < 2 * MT) {
        int m = tid >> 1, side = tid & 1;
        int node = ei[(long)side * N_EDGES + e0 + m];
        const float* xr = x + (long)node * D_FEAT;
        int et = m >> 4, ml = m & 15;
        #pragma unroll
        for (int c = 0; c < D_FEAT; c++) {
            int k = side * D_FEAT + c;
            int lp = ml + 16 * (k >> 3);
            A1f[(et * 64 + lp) * 8 + (k & 7)] = (bf16_t)xr[c];
        }
    }
    __syncthreads();

    // ---- GEMM1: h1 = relu(e @ W1 + b1), K=32 (one step), 5 ft x 2 et ----
    floatx4 acc1[5][2];
    {
        bf16x8 hb[2];
        #pragma unroll
        for (int e = 0; e < 2; e++)
            hb[e] = *(const bf16x8*)&A1f[((eb + e) * 64 + lane) * 8];
        #pragma unroll
        for (int t = 0; t < 5; t++) {
            bf16x8 wf = *(const bf16x8*)&W1P[((wn + 4 * t) * 64 + lane) * 8];
            #pragma unroll
            for (int e = 0; e < 2; e++) {
                floatx4 z = {0.f, 0.f, 0.f, 0.f};
                acc1[t][e] = __builtin_amdgcn_mfma_f32_16x16x32_bf16(wf, hb[e], z, 0, 0, 0);
            }
        }
        __syncthreads();   // all A1f fragment loads done before Hf overwrites alias
    }
    #pragma unroll
    for (int t = 0; t < 5; t++) {
        int n0 = (wn + 4 * t) * 16 + 4 * q;          // 4 consecutive features
        floatx4 bv = (n0 < HIDDEN) ? *(const floatx4*)&b1[n0]
                                   : (floatx4){0.f, 0.f, 0.f, 0.f};
        int ks = n0 >> 5, lp = l16 + 16 * ((n0 >> 3) & 3), j0 = n0 & 7;
        #pragma unroll
        for (int e = 0; e < 2; e++) {
            bf16x4 pk;
            #pragma unroll
            for (int r = 0; r < 4; r++)
                pk[r] = (bf16_t)fmaxf(acc1[t][e][r] + bv[r], 0.f);
            *(bf16x4*)&Hf[(((eb + e) * KS_H + ks) * 64 + lp) * 8 + j0] = pk;
        }
    }
    __syncthreads();

    // ---- GEMM2: h2 = relu(h1 @ W2 + b2), K=320, 5 ft x 2 et ----
    floatx4 acc2[5][2];
    #pragma unroll
    for (int t = 0; t < 5; t++)
        #pragma unroll
        for (int e = 0; e < 2; e++) acc2[t][e] = (floatx4){0.f, 0.f, 0.f, 0.f};
    #pragma unroll 2
    for (int ks = 0; ks < KS_H; ks++) {
        bf16x8 hb[2];
        #pragma unroll
        for (int e = 0; e < 2; e++)
            hb[e] = *(const bf16x8*)&Hf[(((eb + e) * KS_H + ks) * 64 + lane) * 8];
        #pragma unroll
        for (int t = 0; t < 5; t++) {
            bf16x8 wf = *(const bf16x8*)&W2P[(((wn + 4 * t) * KS_H + ks) * 64 + lane) * 8];
            #pragma unroll
            for (int e = 0; e < 2; e++)
                acc2[t][e] = __builtin_amdgcn_mfma_f32_16x16x32_bf16(wf, hb[e], acc2[t][e], 0, 0, 0);
        }
    }
    __syncthreads();   // all Hf(h1) reads done before overwrite
    #pragma unroll
    for (int t = 0; t < 5; t++) {
        int n0 = (wn + 4 * t) * 16 + 4 * q;
        floatx4 bv = (n0 < HIDDEN) ? *(const floatx4*)&b2[n0]
                                   : (floatx4){0.f, 0.f, 0.f, 0.f};
        int ks = n0 >> 5, lp = l16 + 16 * ((n0 >> 3) & 3), j0 = n0 & 7;
        #pragma unroll
        for (int e = 0; e < 2; e++) {
            bf16x4 pk;
            #pragma unroll
            for (int r = 0; r < 4; r++)
                pk[r] = (bf16_t)fmaxf(acc2[t][e][r] + bv[r], 0.f);
            *(bf16x4*)&Hf[(((eb + e) * KS_H + ks) * 64 + lp) * 8 + j0] = pk;
        }
    }
    __syncthreads();

    // ---- GEMM3: messages = h2 @ W3 + b3, KL in-register; f = wn+4t < 13 ----
    floatx4 acc3[4][2];
    #pragma unroll
    for (int t = 0; t < 4; t++)
        #pragma unroll
        for (int e = 0; e < 2; e++) acc3[t][e] = (floatx4){0.f, 0.f, 0.f, 0.f};
    #pragma unroll 2
    for (int ks = 0; ks < KS_H; ks++) {
        bf16x8 hb[2];
        #pragma unroll
        for (int e = 0; e < 2; e++)
            hb[e] = *(const bf16x8*)&Hf[(((eb + e) * KS_H + ks) * 64 + lane) * 8];
        #pragma unroll
        for (int t = 0; t < 4; t++) {
            if (t < cnt3) {
                bf16x8 wf = *(const bf16x8*)&W3P[(((wn + 4 * t) * KS_H + ks) * 64 + lane) * 8];
                #pragma unroll
                for (int e = 0; e < 2; e++)
                    acc3[t][e] = __builtin_amdgcn_mfma_f32_16x16x32_bf16(wf, hb[e], acc3[t][e], 0, 0, 0);
            }
        }
    }
    float s = 0.f;
    #pragma unroll
    for (int t = 0; t < 4; t++) {
        if (t < cnt3) {
            int n0 = (wn + 4 * t) * 16 + 4 * q;      // 4 consecutive features
            if (n0 < OUTC) {                          // 4-runs never straddle 100/200
                floatx4 bv = *(const floatx4*)&b3[n0];
                bool is_mu = (n0 < MSG);
                #pragma unroll
                for (int e = 0; e < 2; e++)
                    #pragma unroll
                    for (int r = 0; r < 4; r++) {
                        float v = acc3[t][e][r] + bv[r];
                        if (is_mu) s += 0.5f * v * v;
                        else       s += 0.5f * (__expf(v) - v - 1.f);
                    }
            }
        }
    }
    #pragma unroll
    for (int off = 32; off; off >>= 1) s += __shfl_down(s, off);
    __syncthreads();                 // Hf dead (all GEMM3 reads done) -> reuse for red
    float* red = (float*)Hf;
    if (lane == 0) red[wave] = s;
    __syncthreads();
    if (tid == 0) {
        float t2 = 0.f;
        #pragma unroll
        for (int i = 0; i < 8; i++) t2 += red[i];
        atomicAdd(out, t2 * (1.0f / N_EDGES));
    }
}

extern "C" void kernel_launch(void* const* d_in, const int* in_sizes, int n_in,
                              void* d_out, int out_size, void* d_ws, size_t ws_size,
                              hipStream_t stream) {
    const float* x      = (const float*)d_in[0];
    const int*   ei     = (const int*)d_in[1];
    const float* y      = (const float*)d_in[2];
    const float* target = (const float*)d_in[3];
    const float* W1     = (const float*)d_in[4];
    const float* b1     = (const float*)d_in[5];
    const float* W2     = (const float*)d_in[6];
    const float* b2     = (const float*)d_in[7];
    const float* W3     = (const float*)d_in[8];
    const float* b3     = (const float*)d_in[9];
    float* out = (float*)d_out;

    bf16_t* W1P = (bf16_t*)d_ws;
    bf16_t* W2P = W1P + NT_H * 512;
    bf16_t* W3P = W2P + NT_H * KS_H * 512;

    hipMemsetAsync(d_out, 0, sizeof(float), stream);
    prep_kernel<<<PREP_BLOCKS + LOSS_BLOCKS, 256, 0, stream>>>(
        W1, W2, W3, W1P, W2P, W3P, y, target, out);
    mlp_kernel<<<N_EDGES / MT, 512, 0, stream>>>(x, ei, W1P, W2P, W3P, b1, b2, b3, out);
}

// Round 10
// 482.565 us; speedup vs baseline: 1.8413x; 1.0620x over previous
//
#include <hip/hip_runtime.h>

#define N_NODES 100000
#define N_EDGES 1000000
#define D_FEAT  6
#define HIDDEN  300
#define HID_P   320          // padded hidden (multiple of 32)
#define MSG     100
#define OUTC    200          // 2*MSG
#define MT      64           // edges per block
#define NT_H    (HID_P/16)   // 20 feature tiles for hidden layers
#define NT_M    13           // 13 feature tiles for messages (208 padded)
#define KS_H    (HID_P/32)   // 10 k-steps of 32

typedef __bf16 bf16_t;
typedef __bf16 bf16x8 __attribute__((ext_vector_type(8)));
typedef __bf16 bf16x4 __attribute__((ext_vector_type(4)));
typedef float  floatx4 __attribute__((ext_vector_type(4)));

// ---------------- prep (weight pack) + base MAE loss, merged --------------------
// Frag-order pack: chunk of 512 el = one (ft,ks) fragment: el = ((ft*KS+ks)*64+lane)*8+j,
// element = W[k][n], n = ft*16+(lane&15), k = ks*32+(lane>>4)*8+j, zero-padded.
#define PREP_BLOCKS 700
#define LOSS_BLOCKS 200
__global__ void prep_kernel(const float* __restrict__ W1, const float* __restrict__ W2,
                            const float* __restrict__ W3, bf16_t* __restrict__ W1P,
                            bf16_t* __restrict__ W2P, bf16_t* __restrict__ W3P,
                            const float* __restrict__ y, const float* __restrict__ t,
                            float* __restrict__ out) {
    if (blockIdx.x >= PREP_BLOCKS) {
        float s = 0.f;
        for (int i = (blockIdx.x - PREP_BLOCKS) * blockDim.x + threadIdx.x;
             i < N_NODES * 2; i += LOSS_BLOCKS * blockDim.x)
            s += fabsf(y[i] - t[i]);
        #pragma unroll
        for (int off = 32; off; off >>= 1) s += __shfl_down(s, off);
        __shared__ float red[4];
        if ((threadIdx.x & 63) == 0) red[threadIdx.x >> 6] = s;
        __syncthreads();
        if (threadIdx.x == 0)
            atomicAdd(out, (red[0] + red[1] + red[2] + red[3]) * (1.0f / N_NODES));
        return;
    }
    const int n1 = NT_H * 512;
    const int n2 = NT_H * KS_H * 512;
    const int n3 = NT_M * KS_H * 512;
    const int total = n1 + n2 + n3;
    for (int id = blockIdx.x * blockDim.x + threadIdx.x; id < total;
         id += PREP_BLOCKS * blockDim.x) {
        if (id < n1) {
            int nt = id >> 9, rem = id & 511, lane = rem >> 3, j = rem & 7;
            int n = nt * 16 + (lane & 15), k = (lane >> 4) * 8 + j;
            float v = (n < HIDDEN && k < 2 * D_FEAT) ? W1[k * HIDDEN + n] : 0.f;
            W1P[id] = (bf16_t)v;
        } else if (id < n1 + n2) {
            int r = id - n1;
            int chunk = r >> 9, rem = r & 511, lane = rem >> 3, j = rem & 7;
            int ks = chunk % KS_H, nt = chunk / KS_H;
            int n = nt * 16 + (lane & 15), k = ks * 32 + (lane >> 4) * 8 + j;
            float v = (n < HIDDEN && k < HIDDEN) ? W2[k * HIDDEN + n] : 0.f;
            W2P[r] = (bf16_t)v;
        } else {
            int r = id - n1 - n2;
            int chunk = r >> 9, rem = r & 511, lane = rem >> 3, j = rem & 7;
            int ks = chunk % KS_H, nt = chunk / KS_H;
            int n = nt * 16 + (lane & 15), k = ks * 32 + (lane >> 4) * 8 + j;
            float v = (n < OUTC && k < HIDDEN) ? W3[k * OUTC + n] : 0.f;
            W3P[r] = (bf16_t)v;
        }
    }
}

// ---------------- fused edge MLP + KL ------------------------------------------
// CONVERGED DESIGN (R1-R9 evidence):
//  * 512 thr = 8 waves, 1(M)x8(N): wave w owns ALL 4 edge-tiles and ft = w+8t
//    (t < cnt_h: 3 for w<4 else 2) for GEMM1/2; GEMM3 ft = w+5t (t < cnt_m:
//    2 for w>=3 else 1). 1x8 has ZERO W-frag duplication -> 350 KB/block L2
//    traffic (~37% of per-CU L2 ceiling); 2x4 duplicates 2x -> 75% = saturated
//    (R9 regression). 1x8 beat 2x4 in both layout generations: 433/420 vs 494/510.
//  * Frag-order LDS (R4/R9): Hf[e][ks][lane][8], conflict-free wave-contiguous
//    ds_read_b128, b64 epilogue writes. Hf = 40960 B; A1f (4 KB) and reduction
//    buffer alias it -> 3 blocks/CU at (512,6) = 6 waves/SIMD (occupancy is the
//    strongest single predictor across R1-R8: 2/SIMD 770, 3/SIMD 538, 6/SIMD 420).
//  * #pragma unroll 2 on K-loops (R3/R9): caps compiler prefetch depth; R4's
//    unpragma'd loops over-unrolled past the 85-reg cliff -> 190 MB scratch.
//    Concurrent live set: acc 48 + hb 16 + wf 4 + misc ~ 72 < 85.
// Layouts (verified absmax 0 R1-R9), operand-swapped D = mfma(A=W, B=H):
// A: m=lane&15, k=(lane>>4)*8+j; B: n=lane&15(edge), k=(lane>>4)*8+j;
// C/D: n(edge)=lane&15, m(feature)=(lane>>4)*4+reg.
__global__ __launch_bounds__(512, 6) void mlp_kernel(
    const float* __restrict__ x, const int* __restrict__ ei,
    const bf16_t* __restrict__ W1P, const bf16_t* __restrict__ W2P,
    const bf16_t* __restrict__ W3P,
    const float* __restrict__ b1, const float* __restrict__ b2,
    const float* __restrict__ b3, float* __restrict__ out) {
    __shared__ __align__(16) bf16_t Hf[4 * KS_H * 64 * 8];    // 40 KB exactly
    bf16_t* A1f = Hf;                                          // aliased 4 KB

    const int tid  = threadIdx.x;
    const int w    = tid >> 6, lane = tid & 63;
    const int q    = lane >> 4, l16 = lane & 15;
    const int cnt_h = (w < 4) ? 3 : 2;
    const int cnt_m = (w >= 3) ? 2 : 1;
    const long e0 = (long)blockIdx.x * MT;

    // zero A1f region (k >= 12 must be 0 for GEMM1's padded K=32): 512x8B = 4KB
    *(ulong*)&A1f[tid * 4] = 0ul;
    __syncthreads();
    // gather: edge features -> A1f fragment order: feat k of edge (et*16+ml)
    // at lane' = ml + 16*(k>>3), slot j = k&7
    if (tid < 2 * MT) {
        int m = tid >> 1, side = tid & 1;
        int node = ei[(long)side * N_EDGES + e0 + m];
        const float* xr = x + (long)node * D_FEAT;
        int et = m >> 4, ml = m & 15;
        #pragma unroll
        for (int c = 0; c < D_FEAT; c++) {
            int k = side * D_FEAT + c;
            int lp = ml + 16 * (k >> 3);
            A1f[(et * 64 + lp) * 8 + (k & 7)] = (bf16_t)xr[c];
        }
    }
    __syncthreads();

    // ---- GEMM1: h1 = relu(e @ W1 + b1), K=32 (one step), <=3 ft x 4 et ----
    floatx4 acc1[3][4];
    {
        bf16x8 hb[4];
        #pragma unroll
        for (int e = 0; e < 4; e++)
            hb[e] = *(const bf16x8*)&A1f[(e * 64 + lane) * 8];
        #pragma unroll
        for (int t = 0; t < 3; t++) {
            if (t < cnt_h) {
                bf16x8 wf = *(const bf16x8*)&W1P[((w + 8 * t) * 64 + lane) * 8];
                #pragma unroll
                for (int e = 0; e < 4; e++) {
                    floatx4 z = {0.f, 0.f, 0.f, 0.f};
                    acc1[t][e] = __builtin_amdgcn_mfma_f32_16x16x32_bf16(wf, hb[e], z, 0, 0, 0);
                }
            }
        }
        __syncthreads();   // all A1f fragment loads done before Hf overwrites alias
    }
    #pragma unroll
    for (int t = 0; t < 3; t++) {
        if (t < cnt_h) {
            int n0 = (w + 8 * t) * 16 + 4 * q;           // 4 consecutive features
            floatx4 bv = (n0 < HIDDEN) ? *(const floatx4*)&b1[n0]
                                       : (floatx4){0.f, 0.f, 0.f, 0.f};
            int ks = n0 >> 5, lp = l16 + 16 * ((n0 >> 3) & 3), j0 = n0 & 7;
            #pragma unroll
            for (int e = 0; e < 4; e++) {
                bf16x4 pk;
                #pragma unroll
                for (int r = 0; r < 4; r++)
                    pk[r] = (bf16_t)fmaxf(acc1[t][e][r] + bv[r], 0.f);
                *(bf16x4*)&Hf[((e * KS_H + ks) * 64 + lp) * 8 + j0] = pk;
            }
        }
    }
    __syncthreads();

    // ---- GEMM2: h2 = relu(h1 @ W2 + b2), K=320, <=3 ft x 4 et ----
    floatx4 acc2[3][4];
    #pragma unroll
    for (int t = 0; t < 3; t++)
        #pragma unroll
        for (int e = 0; e < 4; e++) acc2[t][e] = (floatx4){0.f, 0.f, 0.f, 0.f};
    #pragma unroll 2
    for (int ks = 0; ks < KS_H; ks++) {
        bf16x8 hb[4];
        #pragma unroll
        for (int e = 0; e < 4; e++)
            hb[e] = *(const bf16x8*)&Hf[((e * KS_H + ks) * 64 + lane) * 8];
        #pragma unroll
        for (int t = 0; t < 3; t++) {
            if (t < cnt_h) {
                bf16x8 wf = *(const bf16x8*)&W2P[(((w + 8 * t) * KS_H + ks) * 64 + lane) * 8];
                #pragma unroll
                for (int e = 0; e < 4; e++)
                    acc2[t][e] = __builtin_amdgcn_mfma_f32_16x16x32_bf16(wf, hb[e], acc2[t][e], 0, 0, 0);
            }
        }
    }
    __syncthreads();   // all Hf(h1) reads done before overwrite
    #pragma unroll
    for (int t = 0; t < 3; t++) {
        if (t < cnt_h) {
            int n0 = (w + 8 * t) * 16 + 4 * q;
            floatx4 bv = (n0 < HIDDEN) ? *(const floatx4*)&b2[n0]
                                       : (floatx4){0.f, 0.f, 0.f, 0.f};
            int ks = n0 >> 5, lp = l16 + 16 * ((n0 >> 3) & 3), j0 = n0 & 7;
            #pragma unroll
            for (int e = 0; e < 4; e++) {
                bf16x4 pk;
                #pragma unroll
                for (int r = 0; r < 4; r++)
                    pk[r] = (bf16_t)fmaxf(acc2[t][e][r] + bv[r], 0.f);
                *(bf16x4*)&Hf[((e * KS_H + ks) * 64 + lp) * 8 + j0] = pk;
            }
        }
    }
    __syncthreads();

    // ---- GEMM3: messages = h2 @ W3 + b3, KL in-register; ft = w+5t < 13 ----
    floatx4 acc3[2][4];
    #pragma unroll
    for (int t = 0; t < 2; t++)
        #pragma unroll
        for (int e = 0; e < 4; e++) acc3[t][e] = (floatx4){0.f, 0.f, 0.f, 0.f};
    #pragma unroll 2
    for (int ks = 0; ks < KS_H; ks++) {
        bf16x8 hb[4];
        #pragma unroll
        for (int e = 0; e < 4; e++)
            hb[e] = *(const bf16x8*)&Hf[((e * KS_H + ks) * 64 + lane) * 8];
        #pragma unroll
        for (int t = 0; t < 2; t++) {
            if (t < cnt_m) {
                bf16x8 wf = *(const bf16x8*)&W3P[(((w + 5 * t) * KS_H + ks) * 64 + lane) * 8];
                #pragma unroll
                for (int e = 0; e < 4; e++)
                    acc3[t][e] = __builtin_amdgcn_mfma_f32_16x16x32_bf16(wf, hb[e], acc3[t][e], 0, 0, 0);
            }
        }
    }
    float s = 0.f;
    #pragma unroll
    for (int t = 0; t < 2; t++) {
        if (t < cnt_m) {
            int n0 = (w + 5 * t) * 16 + 4 * q;       // 4 consecutive features
            if (n0 < OUTC) {                          // 4-runs never straddle 100/200
                floatx4 bv = *(const floatx4*)&b3[n0];
                bool is_mu = (n0 < MSG);
                #pragma unroll
                for (int e = 0; e < 4; e++)
                    #pragma unroll
                    for (int r = 0; r < 4; r++) {
                        float v = acc3[t][e][r] + bv[r];
                        if (is_mu) s += 0.5f * v * v;
                        else       s += 0.5f * (__expf(v) - v - 1.f);
                    }
            }
        }
    }
    #pragma unroll
    for (int off = 32; off; off >>= 1) s += __shfl_down(s, off);
    __syncthreads();                 // Hf dead (all GEMM3 reads done) -> reuse for red
    float* red = (float*)Hf;
    if (lane == 0) red[w] = s;
    __syncthreads();
    if (tid == 0) {
        float t2 = 0.f;
        #pragma unroll
        for (int i = 0; i < 8; i++) t2 += red[i];
        atomicAdd(out, t2 * (1.0f / N_EDGES));
    }
}

extern "C" void kernel_launch(void* const* d_in, const int* in_sizes, int n_in,
                              void* d_out, int out_size, void* d_ws, size_t ws_size,
                              hipStream_t stream) {
    const float* x      = (const float*)d_in[0];
    const int*   ei     = (const int*)d_in[1];
    const float* y      = (const float*)d_in[2];
    const float* target = (const float*)d_in[3];
    const float* W1     = (const float*)d_in[4];
    const float* b1     = (const float*)d_in[5];
    const float* W2     = (const float*)d_in[6];
    const float* b2     = (const float*)d_in[7];
    const float* W3     = (const float*)d_in[8];
    const float* b3     = (const float*)d_in[9];
    float* out = (float*)d_out;

    bf16_t* W1P = (bf16_t*)d_ws;
    bf16_t* W2P = W1P + NT_H * 512;
    bf16_t* W3P = W2P + NT_H * KS_H * 512;

    hipMemsetAsync(d_out, 0, sizeof(float), stream);
    prep_kernel<<<PREP_BLOCKS + LOSS_BLOCKS, 256, 0, stream>>>(
        W1, W2, W3, W1P, W2P, W3P, y, target, out);
    mlp_kernel<<<N_EDGES / MT, 512, 0, stream>>>(x, ei, W1P, W2P, W3P, b1, b2, b3, out);
}

// Round 11
// 482.102 us; speedup vs baseline: 1.8431x; 1.0010x over previous
//
#include <hip/hip_runtime.h>

#define N_NODES 100000
#define N_EDGES 1000000
#define D_FEAT  6
#define HIDDEN  300
#define HID_P   320          // padded hidden (multiple of 32)
#define MSG     100
#define OUTC    200          // 2*MSG
#define MT      64           // edges per block
#define NT_H    (HID_P/16)   // 20 feature tiles for hidden layers
#define NT_M    13           // 13 feature tiles for messages (208 padded)
#define KS_H    (HID_P/32)   // 10 k-steps of 32

typedef __bf16 bf16_t;
typedef __bf16 bf16x8 __attribute__((ext_vector_type(8)));
typedef __bf16 bf16x4 __attribute__((ext_vector_type(4)));
typedef float  floatx4 __attribute__((ext_vector_type(4)));

// ---------------- prep (weight pack) + base MAE loss, merged --------------------
// Frag-order pack: chunk of 512 el = one (ft,ks) fragment: el = ((ft*KS+ks)*64+lane)*8+j,
// element = W[k][n], n = ft*16+(lane&15), k = ks*32+(lane>>4)*8+j, zero-padded.
#define PREP_BLOCKS 700
#define LOSS_BLOCKS 200
__global__ void prep_kernel(const float* __restrict__ W1, const float* __restrict__ W2,
                            const float* __restrict__ W3, bf16_t* __restrict__ W1P,
                            bf16_t* __restrict__ W2P, bf16_t* __restrict__ W3P,
                            const float* __restrict__ y, const float* __restrict__ t,
                            float* __restrict__ out) {
    if (blockIdx.x >= PREP_BLOCKS) {
        float s = 0.f;
        for (int i = (blockIdx.x - PREP_BLOCKS) * blockDim.x + threadIdx.x;
             i < N_NODES * 2; i += LOSS_BLOCKS * blockDim.x)
            s += fabsf(y[i] - t[i]);
        #pragma unroll
        for (int off = 32; off; off >>= 1) s += __shfl_down(s, off);
        __shared__ float red[4];
        if ((threadIdx.x & 63) == 0) red[threadIdx.x >> 6] = s;
        __syncthreads();
        if (threadIdx.x == 0)
            atomicAdd(out, (red[0] + red[1] + red[2] + red[3]) * (1.0f / N_NODES));
        return;
    }
    const int n1 = NT_H * 512;
    const int n2 = NT_H * KS_H * 512;
    const int n3 = NT_M * KS_H * 512;
    const int total = n1 + n2 + n3;
    for (int id = blockIdx.x * blockDim.x + threadIdx.x; id < total;
         id += PREP_BLOCKS * blockDim.x) {
        if (id < n1) {
            int nt = id >> 9, rem = id & 511, lane = rem >> 3, j = rem & 7;
            int n = nt * 16 + (lane & 15), k = (lane >> 4) * 8 + j;
            float v = (n < HIDDEN && k < 2 * D_FEAT) ? W1[k * HIDDEN + n] : 0.f;
            W1P[id] = (bf16_t)v;
        } else if (id < n1 + n2) {
            int r = id - n1;
            int chunk = r >> 9, rem = r & 511, lane = rem >> 3, j = rem & 7;
            int ks = chunk % KS_H, nt = chunk / KS_H;
            int n = nt * 16 + (lane & 15), k = ks * 32 + (lane >> 4) * 8 + j;
            float v = (n < HIDDEN && k < HIDDEN) ? W2[k * HIDDEN + n] : 0.f;
            W2P[r] = (bf16_t)v;
        } else {
            int r = id - n1 - n2;
            int chunk = r >> 9, rem = r & 511, lane = rem >> 3, j = rem & 7;
            int ks = chunk % KS_H, nt = chunk / KS_H;
            int n = nt * 16 + (lane & 15), k = ks * 32 + (lane >> 4) * 8 + j;
            float v = (n < OUTC && k < HIDDEN) ? W3[k * OUTC + n] : 0.f;
            W3P[r] = (bf16_t)v;
        }
    }
}

// ---------------- fused edge MLP + KL ------------------------------------------
// CONVERGED DESIGN (R1-R10 evidence):
//  * 512 thr = 8 waves, 1(M)x8(N): wave w owns ALL 4 edge-tiles and ft = w+8t
//    (t < cnt_h: 3 for w<4 else 2) for GEMM1/2; GEMM3 ft = w+5t (t < cnt_m).
//    1x8 has ZERO W-frag duplication (176 KB/block L2) and beat 2x4 in both
//    layout generations (433/420/481 vs 494/510) despite 2x4 halving LDS reads.
//  * Frag-order LDS: Hf[e][ks][lane][8], conflict-free wave-contiguous
//    ds_read_b128, b64 epilogue writes. Hf = 40960 B; A1f (4 KB) and the
//    reduction buffer alias it -> 3 blocks/CU at (512,6) = 6 waves/SIMD.
//  * REGISTER DISCIPLINE (R4/R10 lesson): 48-acc GEMM2 tolerates NO unroll
//    doubling of operand buffers. unroll 2 -> live = 48 + 2x(16 hb + 4 wf)
//    + addr > 85 -> ~18 B/thread scratch (R10: 146 MB WRITE). unroll 1 ->
//    live = 48 + 16 + 4 + addr ~ 80 < 85. Latency per ks-iter (~200 cyc L2
//    wf loads) is hidden by 6 waves/SIMD TLP.
// Layouts (verified absmax 0 R1-R10), operand-swapped D = mfma(A=W, B=H):
// A: m=lane&15, k=(lane>>4)*8+j; B: n=lane&15(edge), k=(lane>>4)*8+j;
// C/D: n(edge)=lane&15, m(feature)=(lane>>4)*4+reg.
__global__ __launch_bounds__(512, 6) void mlp_kernel(
    const float* __restrict__ x, const int* __restrict__ ei,
    const bf16_t* __restrict__ W1P, const bf16_t* __restrict__ W2P,
    const bf16_t* __restrict__ W3P,
    const float* __restrict__ b1, const float* __restrict__ b2,
    const float* __restrict__ b3, float* __restrict__ out) {
    __shared__ __align__(16) bf16_t Hf[4 * KS_H * 64 * 8];    // 40 KB exactly
    bf16_t* A1f = Hf;                                          // aliased 4 KB

    const int tid  = threadIdx.x;
    const int w    = tid >> 6, lane = tid & 63;
    const int q    = lane >> 4, l16 = lane & 15;
    const int cnt_h = (w < 4) ? 3 : 2;
    const int cnt_m = (w >= 3) ? 2 : 1;
    const long e0 = (long)blockIdx.x * MT;

    // zero A1f region (k >= 12 must be 0 for GEMM1's padded K=32): 512x8B = 4KB
    *(ulong*)&A1f[tid * 4] = 0ul;
    __syncthreads();
    // gather: edge features -> A1f fragment order: feat k of edge (et*16+ml)
    // at lane' = ml + 16*(k>>3), slot j = k&7
    if (tid < 2 * MT) {
        int m = tid >> 1, side = tid & 1;
        int node = ei[(long)side * N_EDGES + e0 + m];
        const float* xr = x + (long)node * D_FEAT;
        int et = m >> 4, ml = m & 15;
        #pragma unroll
        for (int c = 0; c < D_FEAT; c++) {
            int k = side * D_FEAT + c;
            int lp = ml + 16 * (k >> 3);
            A1f[(et * 64 + lp) * 8 + (k & 7)] = (bf16_t)xr[c];
        }
    }
    __syncthreads();

    // ---- GEMM1: h1 = relu(e @ W1 + b1), K=32 (one step), <=3 ft x 4 et ----
    floatx4 acc1[3][4];
    {
        bf16x8 hb[4];
        #pragma unroll
        for (int e = 0; e < 4; e++)
            hb[e] = *(const bf16x8*)&A1f[(e * 64 + lane) * 8];
        #pragma unroll
        for (int t = 0; t < 3; t++) {
            if (t < cnt_h) {
                bf16x8 wf = *(const bf16x8*)&W1P[((w + 8 * t) * 64 + lane) * 8];
                #pragma unroll
                for (int e = 0; e < 4; e++) {
                    floatx4 z = {0.f, 0.f, 0.f, 0.f};
                    acc1[t][e] = __builtin_amdgcn_mfma_f32_16x16x32_bf16(wf, hb[e], z, 0, 0, 0);
                }
            }
        }
        __syncthreads();   // all A1f fragment loads done before Hf overwrites alias
    }
    #pragma unroll
    for (int t = 0; t < 3; t++) {
        if (t < cnt_h) {
            int n0 = (w + 8 * t) * 16 + 4 * q;           // 4 consecutive features
            floatx4 bv = (n0 < HIDDEN) ? *(const floatx4*)&b1[n0]
                                       : (floatx4){0.f, 0.f, 0.f, 0.f};
            int ks = n0 >> 5, lp = l16 + 16 * ((n0 >> 3) & 3), j0 = n0 & 7;
            #pragma unroll
            for (int e = 0; e < 4; e++) {
                bf16x4 pk;
                #pragma unroll
                for (int r = 0; r < 4; r++)
                    pk[r] = (bf16_t)fmaxf(acc1[t][e][r] + bv[r], 0.f);
                *(bf16x4*)&Hf[((e * KS_H + ks) * 64 + lp) * 8 + j0] = pk;
            }
        }
    }
    __syncthreads();

    // ---- GEMM2: h2 = relu(h1 @ W2 + b2), K=320, <=3 ft x 4 et ----
    floatx4 acc2[3][4];
    #pragma unroll
    for (int t = 0; t < 3; t++)
        #pragma unroll
        for (int e = 0; e < 4; e++) acc2[t][e] = (floatx4){0.f, 0.f, 0.f, 0.f};
    #pragma unroll 1
    for (int ks = 0; ks < KS_H; ks++) {
        bf16x8 hb[4];
        #pragma unroll
        for (int e = 0; e < 4; e++)
            hb[e] = *(const bf16x8*)&Hf[((e * KS_H + ks) * 64 + lane) * 8];
        #pragma unroll
        for (int t = 0; t < 3; t++) {
            if (t < cnt_h) {
                bf16x8 wf = *(const bf16x8*)&W2P[(((w + 8 * t) * KS_H + ks) * 64 + lane) * 8];
                #pragma unroll
                for (int e = 0; e < 4; e++)
                    acc2[t][e] = __builtin_amdgcn_mfma_f32_16x16x32_bf16(wf, hb[e], acc2[t][e], 0, 0, 0);
            }
        }
    }
    __syncthreads();   // all Hf(h1) reads done before overwrite
    #pragma unroll
    for (int t = 0; t < 3; t++) {
        if (t < cnt_h) {
            int n0 = (w + 8 * t) * 16 + 4 * q;
            floatx4 bv = (n0 < HIDDEN) ? *(const floatx4*)&b2[n0]
                                       : (floatx4){0.f, 0.f, 0.f, 0.f};
            int ks = n0 >> 5, lp = l16 + 16 * ((n0 >> 3) & 3), j0 = n0 & 7;
            #pragma unroll
            for (int e = 0; e < 4; e++) {
                bf16x4 pk;
                #pragma unroll
                for (int r = 0; r < 4; r++)
                    pk[r] = (bf16_t)fmaxf(acc2[t][e][r] + bv[r], 0.f);
                *(bf16x4*)&Hf[((e * KS_H + ks) * 64 + lp) * 8 + j0] = pk;
            }
        }
    }
    __syncthreads();

    // ---- GEMM3: messages = h2 @ W3 + b3, KL in-register; ft = w+5t < 13 ----
    floatx4 acc3[2][4];
    #pragma unroll
    for (int t = 0; t < 2; t++)
        #pragma unroll
        for (int e = 0; e < 4; e++) acc3[t][e] = (floatx4){0.f, 0.f, 0.f, 0.f};
    #pragma unroll 1
    for (int ks = 0; ks < KS_H; ks++) {
        bf16x8 hb[4];
        #pragma unroll
        for (int e = 0; e < 4; e++)
            hb[e] = *(const bf16x8*)&Hf[((e * KS_H + ks) * 64 + lane) * 8];
        #pragma unroll
        for (int t = 0; t < 2; t++) {
            if (t < cnt_m) {
                bf16x8 wf = *(const bf16x8*)&W3P[(((w + 5 * t) * KS_H + ks) * 64 + lane) * 8];
                #pragma unroll
                for (int e = 0; e < 4; e++)
                    acc3[t][e] = __builtin_amdgcn_mfma_f32_16x16x32_bf16(wf, hb[e], acc3[t][e], 0, 0, 0);
            }
        }
    }
    float s = 0.f;
    #pragma unroll
    for (int t = 0; t < 2; t++) {
        if (t < cnt_m) {
            int n0 = (w + 5 * t) * 16 + 4 * q;       // 4 consecutive features
            if (n0 < OUTC) {                          // 4-runs never straddle 100/200
                floatx4 bv = *(const floatx4*)&b3[n0];
                bool is_mu = (n0 < MSG);
                #pragma unroll
                for (int e = 0; e < 4; e++)
                    #pragma unroll
                    for (int r = 0; r < 4; r++) {
                        float v = acc3[t][e][r] + bv[r];
                        if (is_mu) s += 0.5f * v * v;
                        else       s += 0.5f * (__expf(v) - v - 1.f);
                    }
            }
        }
    }
    #pragma unroll
    for (int off = 32; off; off >>= 1) s += __shfl_down(s, off);
    __syncthreads();                 // Hf dead (all GEMM3 reads done) -> reuse for red
    float* red = (float*)Hf;
    if (lane == 0) red[w] = s;
    __syncthreads();
    if (tid == 0) {
        float t2 = 0.f;
        #pragma unroll
        for (int i = 0; i < 8; i++) t2 += red[i];
        atomicAdd(out, t2 * (1.0f / N_EDGES));
    }
}

extern "C" void kernel_launch(void* const* d_in, const int* in_sizes, int n_in,
                              void* d_out, int out_size, void* d_ws, size_t ws_size,
                              hipStream_t stream) {
    const float* x      = (const float*)d_in[0];
    const int*   ei     = (const int*)d_in[1];
    const float* y      = (const float*)d_in[2];
    const float* target = (const float*)d_in[3];
    const float* W1     = (const float*)d_in[4];
    const float* b1     = (const float*)d_in[5];
    const float* W2     = (const float*)d_in[6];
    const float* b2     = (const float*)d_in[7];
    const float* W3     = (const float*)d_in[8];
    const float* b3     = (const float*)d_in[9];
    float* out = (float*)d_out;

    bf16_t* W1P = (bf16_t*)d_ws;
    bf16_t* W2P = W1P + NT_H * 512;
    bf16_t* W3P = W2P + NT_H * KS_H * 512;

    hipMemsetAsync(d_out, 0, sizeof(float), stream);
    prep_kernel<<<PREP_BLOCKS + LOSS_BLOCKS, 256, 0, stream>>>(
        W1, W2, W3, W1P, W2P, W3P, y, target, out);
    mlp_kernel<<<N_EDGES / MT, 512, 0, stream>>>(x, ei, W1P, W2P, W3P, b1, b2, b3, out);
}